// Round 6
// baseline (118.974 us; speedup 1.0000x reference)
//
#include <hip/hip_runtime.h>

// Problem constants (from reference setup_inputs)
#define BB   32
#define MM   512
#define NN   256
#define HH   128
#define WW   128
#define HWSZ (HH * WW)            // 16384 cells per batch

#define CELLS_PER_BLK 1024        // flat-cells owned by one block (4 per thread)
#define BLKS_PER_B    (HWSZ / CELLS_PER_BLK)   // 16
#define NSPLIT        1           // full n-range per block
#define NCHUNK        (NN / NSPLIT)            // 256 n-values per block
#define KCAP          8           // per-thread private entity capacity (4 cells)

typedef float f32x4 __attribute__((ext_vector_type(4)));

// One block = (b, 1024 cells, all 256 n). 256 threads; thread t owns cells
// F0+4t .. F0+4t+3. Phase 1: scan the batch's 512 entities, keep the ~32 that
// land in this block's cell range (LDS). Phase 2: distribute to per-thread
// registers (compile-time-indexed). Phase 3: stream over n in groups of 8,
// accumulating an 8x4 (n x cell) register tile and storing 8 nontemporal 16B
// stores per iteration — every output element written exactly once,
// evict-first so the 537 MB write stream doesn't churn L2.
__global__ __launch_bounds__(256)
void scatter_stream_kernel(const float* __restrict__ x,
                           const int*   __restrict__ loc,
                           float*       __restrict__ out) {
    __shared__ int s_m[MM];
    __shared__ int s_c[MM];
    __shared__ int s_cnt;

    const int t    = threadIdx.x;                       // 0..255
    const int blk  = blockIdx.x;                        // 0..511
    const int b    = blk / BLKS_PER_B;
    const int sub  = blk % BLKS_PER_B;
    const int F0   = sub * CELLS_PER_BLK;

    if (t == 0) s_cnt = 0;
    __syncthreads();

    // ---- Phase 1: scan this batch's entities, keep ones in [F0, F0+1024) ----
    const int* lb = loc + b * MM * 2;
    #pragma unroll
    for (int i = 0; i < 2; ++i) {
        const int m  = t + i * 256;
        const int2 yx = *reinterpret_cast<const int2*>(lb + 2 * m);
        const int c  = yx.x * WW + yx.y - F0;
        if ((unsigned)c < (unsigned)CELLS_PER_BLK) {
            const int idx = atomicAdd(&s_cnt, 1);
            s_m[idx] = m;
            s_c[idx] = c;
        }
    }
    __syncthreads();
    const int cnt = s_cnt;                              // avg ~32, max 512

    // ---- Phase 2: per-thread private list for cells 4t..4t+3 ----
    int pk[KCAP];                                        // (m<<2)|slot — static-indexed only
    #pragma unroll
    for (int k = 0; k < KCAP; ++k) pk[k] = 0;
    int myCnt = 0;
    for (int e = 0; e < cnt; ++e) {
        const int c = s_c[e];
        if ((c >> 2) == t) {
            const int v = (s_m[e] << 2) | (c & 3);
            #pragma unroll
            for (int k = 0; k < KCAP; ++k)
                if (myCnt == k) pk[k] = v;               // compile-time index
            ++myCnt;
        }
    }
    const bool ovf = (myCnt > KCAP);                     // ~P(1e-13): LDS-rescan path
    if (ovf) myCnt = 0;

    // wave-uniform trip count
    int wmax = myCnt;
    #pragma unroll
    for (int s = 1; s < 64; s <<= 1)
        wmax = max(wmax, __shfl_xor(wmax, s));
    wmax = __builtin_amdgcn_readfirstlane(wmax);
    const bool ovfAny = (__ballot(ovf) != 0ull);         // wave-uniform

    // ---- Phase 3: stream over n in groups of 8 ----
    const float* xb = x + (size_t)b * MM * NN;           // + m*NN + n0
    float* ob = out + (size_t)b * NN * HWSZ + F0 + 4 * t;

    if (!ovfAny) {
        for (int n0 = 0; n0 < NCHUNK; n0 += 8) {
            f32x4 a0 = {0.f, 0.f, 0.f, 0.f};             // n-offset 0, cells 0..3
            f32x4 a1 = {0.f, 0.f, 0.f, 0.f};
            f32x4 a2 = {0.f, 0.f, 0.f, 0.f};
            f32x4 a3 = {0.f, 0.f, 0.f, 0.f};
            f32x4 a4 = {0.f, 0.f, 0.f, 0.f};
            f32x4 a5 = {0.f, 0.f, 0.f, 0.f};
            f32x4 a6 = {0.f, 0.f, 0.f, 0.f};
            f32x4 a7 = {0.f, 0.f, 0.f, 0.f};             // n-offset 7
            #pragma unroll
            for (int k = 0; k < KCAP; ++k) {
                if (k >= wmax) break;                    // wave-uniform break
                if (k < myCnt) {
                    const int m = pk[k] >> 2;
                    const float* xp = xb + (size_t)m * NN + n0;
                    const f32x4 xlo = *reinterpret_cast<const f32x4*>(xp);
                    const f32x4 xhi = *reinterpret_cast<const f32x4*>(xp + 4);
                    switch (pk[k] & 3) {
                        case 0: a0.x += xlo.x; a1.x += xlo.y; a2.x += xlo.z; a3.x += xlo.w;
                                a4.x += xhi.x; a5.x += xhi.y; a6.x += xhi.z; a7.x += xhi.w; break;
                        case 1: a0.y += xlo.x; a1.y += xlo.y; a2.y += xlo.z; a3.y += xlo.w;
                                a4.y += xhi.x; a5.y += xhi.y; a6.y += xhi.z; a7.y += xhi.w; break;
                        case 2: a0.z += xlo.x; a1.z += xlo.y; a2.z += xlo.z; a3.z += xlo.w;
                                a4.z += xhi.x; a5.z += xhi.y; a6.z += xhi.z; a7.z += xhi.w; break;
                        default:a0.w += xlo.x; a1.w += xlo.y; a2.w += xlo.z; a3.w += xlo.w;
                                a4.w += xhi.x; a5.w += xhi.y; a6.w += xhi.z; a7.w += xhi.w; break;
                    }
                }
            }
            float* op = ob + (size_t)n0 * HWSZ;
            __builtin_nontemporal_store(a0, reinterpret_cast<f32x4*>(op));
            __builtin_nontemporal_store(a1, reinterpret_cast<f32x4*>(op + (size_t)HWSZ));
            __builtin_nontemporal_store(a2, reinterpret_cast<f32x4*>(op + (size_t)2 * HWSZ));
            __builtin_nontemporal_store(a3, reinterpret_cast<f32x4*>(op + (size_t)3 * HWSZ));
            __builtin_nontemporal_store(a4, reinterpret_cast<f32x4*>(op + (size_t)4 * HWSZ));
            __builtin_nontemporal_store(a5, reinterpret_cast<f32x4*>(op + (size_t)5 * HWSZ));
            __builtin_nontemporal_store(a6, reinterpret_cast<f32x4*>(op + (size_t)6 * HWSZ));
            __builtin_nontemporal_store(a7, reinterpret_cast<f32x4*>(op + (size_t)7 * HWSZ));
        }
    } else {
        // bulletproof fallback: rescan LDS list each n-group (never taken for
        // this input distribution; wave-uniform branch)
        for (int n0 = 0; n0 < NCHUNK; n0 += 8) {
            f32x4 a0 = {0.f, 0.f, 0.f, 0.f};
            f32x4 a1 = {0.f, 0.f, 0.f, 0.f};
            f32x4 a2 = {0.f, 0.f, 0.f, 0.f};
            f32x4 a3 = {0.f, 0.f, 0.f, 0.f};
            f32x4 a4 = {0.f, 0.f, 0.f, 0.f};
            f32x4 a5 = {0.f, 0.f, 0.f, 0.f};
            f32x4 a6 = {0.f, 0.f, 0.f, 0.f};
            f32x4 a7 = {0.f, 0.f, 0.f, 0.f};
            for (int e = 0; e < cnt; ++e) {
                const int c = s_c[e];
                if ((c >> 2) == t) {
                    const float* xp = xb + (size_t)s_m[e] * NN + n0;
                    const f32x4 xlo = *reinterpret_cast<const f32x4*>(xp);
                    const f32x4 xhi = *reinterpret_cast<const f32x4*>(xp + 4);
                    switch (c & 3) {
                        case 0: a0.x += xlo.x; a1.x += xlo.y; a2.x += xlo.z; a3.x += xlo.w;
                                a4.x += xhi.x; a5.x += xhi.y; a6.x += xhi.z; a7.x += xhi.w; break;
                        case 1: a0.y += xlo.x; a1.y += xlo.y; a2.y += xlo.z; a3.y += xlo.w;
                                a4.y += xhi.x; a5.y += xhi.y; a6.y += xhi.z; a7.y += xhi.w; break;
                        case 2: a0.z += xlo.x; a1.z += xlo.y; a2.z += xlo.z; a3.z += xlo.w;
                                a4.z += xhi.x; a5.z += xhi.y; a6.z += xhi.z; a7.z += xhi.w; break;
                        default:a0.w += xlo.x; a1.w += xlo.y; a2.w += xlo.z; a3.w += xlo.w;
                                a4.w += xhi.x; a5.w += xhi.y; a6.w += xhi.z; a7.w += xhi.w; break;
                    }
                }
            }
            float* op = ob + (size_t)n0 * HWSZ;
            __builtin_nontemporal_store(a0, reinterpret_cast<f32x4*>(op));
            __builtin_nontemporal_store(a1, reinterpret_cast<f32x4*>(op + (size_t)HWSZ));
            __builtin_nontemporal_store(a2, reinterpret_cast<f32x4*>(op + (size_t)2 * HWSZ));
            __builtin_nontemporal_store(a3, reinterpret_cast<f32x4*>(op + (size_t)3 * HWSZ));
            __builtin_nontemporal_store(a4, reinterpret_cast<f32x4*>(op + (size_t)4 * HWSZ));
            __builtin_nontemporal_store(a5, reinterpret_cast<f32x4*>(op + (size_t)5 * HWSZ));
            __builtin_nontemporal_store(a6, reinterpret_cast<f32x4*>(op + (size_t)6 * HWSZ));
            __builtin_nontemporal_store(a7, reinterpret_cast<f32x4*>(op + (size_t)7 * HWSZ));
        }
    }
}

extern "C" void kernel_launch(void* const* d_in, const int* in_sizes, int n_in,
                              void* d_out, int out_size, void* d_ws, size_t ws_size,
                              hipStream_t stream) {
    const float* x   = (const float*)d_in[0];
    const int*   loc = (const int*)d_in[1];
    float*       out = (float*)d_out;

    const int nblk = BB * BLKS_PER_B * NSPLIT;           // 512 blocks
    scatter_stream_kernel<<<nblk, 256, 0, stream>>>(x, loc, out);
}

// Round 7
// 107.289 us; speedup vs baseline: 1.1089x; 1.1089x over previous
//
#include <hip/hip_runtime.h>

// Problem constants (from reference setup_inputs)
#define BB   32
#define MM   512
#define NN   256
#define HH   128
#define WW   128
#define HWSZ (HH * WW)            // 16384 cells per batch

#define CELLS_PER_BLK 1024        // flat-cells owned by one block (4 per thread)
#define BLKS_PER_B    (HWSZ / CELLS_PER_BLK)   // 16
#define NSPLIT        2           // split n-range across blocks -> 1024 blocks
#define NCHUNK        (NN / NSPLIT)            // 128 n-values per block
#define KCAP          8           // per-thread private entity capacity (4 cells)

typedef float f32x4 __attribute__((ext_vector_type(4)));

// One block = (b, 1024 cells, 128 n). 256 threads; thread t owns cells
// F0+4t .. F0+4t+3. Phase 1: scan the batch's 512 entities, keep the ~32 that
// land in this block's cell range (LDS). Phase 2: distribute to per-thread
// registers (compile-time-indexed). Phase 3: stream over n in groups of 8,
// accumulating an 8x4 (n x cell) register tile and storing 8 nontemporal 16B
// stores per iteration — every output element written exactly once,
// evict-first so the 537 MB write stream doesn't churn L2.
// 1024 blocks = 4 blocks/CU = 16 waves/CU (R6 lesson: 8 waves/CU can't hide
// the NT-store drain; keep >=16).
__global__ __launch_bounds__(256)
void scatter_stream_kernel(const float* __restrict__ x,
                           const int*   __restrict__ loc,
                           float*       __restrict__ out) {
    __shared__ int s_m[MM];
    __shared__ int s_c[MM];
    __shared__ int s_cnt;

    const int t    = threadIdx.x;                       // 0..255
    const int blk  = blockIdx.x;                        // 0..1023
    const int b    = blk / (BLKS_PER_B * NSPLIT);
    const int rem  = blk % (BLKS_PER_B * NSPLIT);
    const int sub  = rem / NSPLIT;
    const int half = rem % NSPLIT;
    const int F0   = sub * CELLS_PER_BLK;
    const int n_lo = half * NCHUNK;

    if (t == 0) s_cnt = 0;
    __syncthreads();

    // ---- Phase 1: scan this batch's entities, keep ones in [F0, F0+1024) ----
    const int* lb = loc + b * MM * 2;
    #pragma unroll
    for (int i = 0; i < 2; ++i) {
        const int m  = t + i * 256;
        const int2 yx = *reinterpret_cast<const int2*>(lb + 2 * m);
        const int c  = yx.x * WW + yx.y - F0;
        if ((unsigned)c < (unsigned)CELLS_PER_BLK) {
            const int idx = atomicAdd(&s_cnt, 1);
            s_m[idx] = m;
            s_c[idx] = c;
        }
    }
    __syncthreads();
    const int cnt = s_cnt;                              // avg ~32, max 512

    // ---- Phase 2: per-thread private list for cells 4t..4t+3 ----
    int pk[KCAP];                                        // (m<<2)|slot — static-indexed only
    #pragma unroll
    for (int k = 0; k < KCAP; ++k) pk[k] = 0;
    int myCnt = 0;
    for (int e = 0; e < cnt; ++e) {
        const int c = s_c[e];
        if ((c >> 2) == t) {
            const int v = (s_m[e] << 2) | (c & 3);
            #pragma unroll
            for (int k = 0; k < KCAP; ++k)
                if (myCnt == k) pk[k] = v;               // compile-time index
            ++myCnt;
        }
    }
    const bool ovf = (myCnt > KCAP);                     // ~P(1e-13): LDS-rescan path
    if (ovf) myCnt = 0;

    // wave-uniform trip count
    int wmax = myCnt;
    #pragma unroll
    for (int s = 1; s < 64; s <<= 1)
        wmax = max(wmax, __shfl_xor(wmax, s));
    wmax = __builtin_amdgcn_readfirstlane(wmax);
    const bool ovfAny = (__ballot(ovf) != 0ull);         // wave-uniform

    // ---- Phase 3: stream over n in groups of 8 ----
    const float* xb = x + (size_t)b * MM * NN + n_lo;    // + m*NN + n0
    float* ob = out + (size_t)b * NN * HWSZ + (size_t)n_lo * HWSZ + F0 + 4 * t;

    if (!ovfAny) {
        for (int n0 = 0; n0 < NCHUNK; n0 += 8) {
            f32x4 a0 = {0.f, 0.f, 0.f, 0.f};             // n-offset 0, cells 0..3
            f32x4 a1 = {0.f, 0.f, 0.f, 0.f};
            f32x4 a2 = {0.f, 0.f, 0.f, 0.f};
            f32x4 a3 = {0.f, 0.f, 0.f, 0.f};
            f32x4 a4 = {0.f, 0.f, 0.f, 0.f};
            f32x4 a5 = {0.f, 0.f, 0.f, 0.f};
            f32x4 a6 = {0.f, 0.f, 0.f, 0.f};
            f32x4 a7 = {0.f, 0.f, 0.f, 0.f};             // n-offset 7
            #pragma unroll
            for (int k = 0; k < KCAP; ++k) {
                if (k >= wmax) break;                    // wave-uniform break
                if (k < myCnt) {
                    const int m = pk[k] >> 2;
                    const float* xp = xb + (size_t)m * NN + n0;
                    const f32x4 xlo = *reinterpret_cast<const f32x4*>(xp);
                    const f32x4 xhi = *reinterpret_cast<const f32x4*>(xp + 4);
                    switch (pk[k] & 3) {
                        case 0: a0.x += xlo.x; a1.x += xlo.y; a2.x += xlo.z; a3.x += xlo.w;
                                a4.x += xhi.x; a5.x += xhi.y; a6.x += xhi.z; a7.x += xhi.w; break;
                        case 1: a0.y += xlo.x; a1.y += xlo.y; a2.y += xlo.z; a3.y += xlo.w;
                                a4.y += xhi.x; a5.y += xhi.y; a6.y += xhi.z; a7.y += xhi.w; break;
                        case 2: a0.z += xlo.x; a1.z += xlo.y; a2.z += xlo.z; a3.z += xlo.w;
                                a4.z += xhi.x; a5.z += xhi.y; a6.z += xhi.z; a7.z += xhi.w; break;
                        default:a0.w += xlo.x; a1.w += xlo.y; a2.w += xlo.z; a3.w += xlo.w;
                                a4.w += xhi.x; a5.w += xhi.y; a6.w += xhi.z; a7.w += xhi.w; break;
                    }
                }
            }
            float* op = ob + (size_t)n0 * HWSZ;
            __builtin_nontemporal_store(a0, reinterpret_cast<f32x4*>(op));
            __builtin_nontemporal_store(a1, reinterpret_cast<f32x4*>(op + (size_t)HWSZ));
            __builtin_nontemporal_store(a2, reinterpret_cast<f32x4*>(op + (size_t)2 * HWSZ));
            __builtin_nontemporal_store(a3, reinterpret_cast<f32x4*>(op + (size_t)3 * HWSZ));
            __builtin_nontemporal_store(a4, reinterpret_cast<f32x4*>(op + (size_t)4 * HWSZ));
            __builtin_nontemporal_store(a5, reinterpret_cast<f32x4*>(op + (size_t)5 * HWSZ));
            __builtin_nontemporal_store(a6, reinterpret_cast<f32x4*>(op + (size_t)6 * HWSZ));
            __builtin_nontemporal_store(a7, reinterpret_cast<f32x4*>(op + (size_t)7 * HWSZ));
        }
    } else {
        // bulletproof fallback: rescan LDS list each n-group (never taken for
        // this input distribution; wave-uniform branch)
        for (int n0 = 0; n0 < NCHUNK; n0 += 8) {
            f32x4 a0 = {0.f, 0.f, 0.f, 0.f};
            f32x4 a1 = {0.f, 0.f, 0.f, 0.f};
            f32x4 a2 = {0.f, 0.f, 0.f, 0.f};
            f32x4 a3 = {0.f, 0.f, 0.f, 0.f};
            f32x4 a4 = {0.f, 0.f, 0.f, 0.f};
            f32x4 a5 = {0.f, 0.f, 0.f, 0.f};
            f32x4 a6 = {0.f, 0.f, 0.f, 0.f};
            f32x4 a7 = {0.f, 0.f, 0.f, 0.f};
            for (int e = 0; e < cnt; ++e) {
                const int c = s_c[e];
                if ((c >> 2) == t) {
                    const float* xp = xb + (size_t)s_m[e] * NN + n0;
                    const f32x4 xlo = *reinterpret_cast<const f32x4*>(xp);
                    const f32x4 xhi = *reinterpret_cast<const f32x4*>(xp + 4);
                    switch (c & 3) {
                        case 0: a0.x += xlo.x; a1.x += xlo.y; a2.x += xlo.z; a3.x += xlo.w;
                                a4.x += xhi.x; a5.x += xhi.y; a6.x += xhi.z; a7.x += xhi.w; break;
                        case 1: a0.y += xlo.x; a1.y += xlo.y; a2.y += xlo.z; a3.y += xlo.w;
                                a4.y += xhi.x; a5.y += xhi.y; a6.y += xhi.z; a7.y += xhi.w; break;
                        case 2: a0.z += xlo.x; a1.z += xlo.y; a2.z += xlo.z; a3.z += xlo.w;
                                a4.z += xhi.x; a5.z += xhi.y; a6.z += xhi.z; a7.z += xhi.w; break;
                        default:a0.w += xlo.x; a1.w += xlo.y; a2.w += xlo.z; a3.w += xlo.w;
                                a4.w += xhi.x; a5.w += xhi.y; a6.w += xhi.z; a7.w += xhi.w; break;
                    }
                }
            }
            float* op = ob + (size_t)n0 * HWSZ;
            __builtin_nontemporal_store(a0, reinterpret_cast<f32x4*>(op));
            __builtin_nontemporal_store(a1, reinterpret_cast<f32x4*>(op + (size_t)HWSZ));
            __builtin_nontemporal_store(a2, reinterpret_cast<f32x4*>(op + (size_t)2 * HWSZ));
            __builtin_nontemporal_store(a3, reinterpret_cast<f32x4*>(op + (size_t)3 * HWSZ));
            __builtin_nontemporal_store(a4, reinterpret_cast<f32x4*>(op + (size_t)4 * HWSZ));
            __builtin_nontemporal_store(a5, reinterpret_cast<f32x4*>(op + (size_t)5 * HWSZ));
            __builtin_nontemporal_store(a6, reinterpret_cast<f32x4*>(op + (size_t)6 * HWSZ));
            __builtin_nontemporal_store(a7, reinterpret_cast<f32x4*>(op + (size_t)7 * HWSZ));
        }
    }
}

extern "C" void kernel_launch(void* const* d_in, const int* in_sizes, int n_in,
                              void* d_out, int out_size, void* d_ws, size_t ws_size,
                              hipStream_t stream) {
    const float* x   = (const float*)d_in[0];
    const int*   loc = (const int*)d_in[1];
    float*       out = (float*)d_out;

    const int nblk = BB * BLKS_PER_B * NSPLIT;           // 1024 blocks
    scatter_stream_kernel<<<nblk, 256, 0, stream>>>(x, loc, out);
}